// Round 20
// baseline (266.309 us; speedup 1.0000x reference)
//
#include <hip/hip_runtime.h>
#include <hip/hip_bf16.h>
#include <math.h>

#define NN 8192
#define HD 128
#define NB 2
#define EPSF 1e-6f
#define BM 64
#define BK 128                // fp32 K per step (tile = 64x128x4B = 32 KB)
#define NSTEP (NN / BK)       // 64

typedef __attribute__((ext_vector_type(8))) __bf16 bf16x8;
typedef __attribute__((ext_vector_type(4))) float f32x4;

// ---------------- Kernel 1: norm = rsqrt(sum|adj_row| + eps) -----------------
__global__ __launch_bounds__(256) void k_degree(const float* __restrict__ adj,
                                                float* __restrict__ norm) {
    const int row  = blockIdx.x * 4 + (threadIdx.x >> 6);
    const int lane = threadIdx.x & 63;
    const float4* p = (const float4*)(adj + (size_t)row * NN);
    float s = 0.f;
#pragma unroll
    for (int i = 0; i < 32; ++i) {
        float4 v = p[(size_t)i * 64 + lane];
        s += fabsf(v.x) + fabsf(v.y) + fabsf(v.z) + fabsf(v.w);
    }
#pragma unroll
    for (int off = 32; off > 0; off >>= 1) s += __shfl_down(s, off);
    if (lane == 0) norm[row] = rsqrtf(s + EPSF);
}

// --- Kernel 2: snT2[b][n/32][h][n&31] = bf16( (x@W)[b][n][h] * norm[b][n] ) --
// K-panel-major layout (R15-verified): gemm B loads are 1 KB/wave contiguous.
__global__ __launch_bounds__(256) void k_support(const float* __restrict__ x,
                                                 const float* __restrict__ W,
                                                 const float* __restrict__ norm,
                                                 __hip_bfloat16* __restrict__ snT2) {
    const int b  = blockIdx.x >> 9;
    const int n0 = (blockIdx.x & 511) * 16;
    __shared__ float xs[16][132];
    const int t = threadIdx.x;
    {
        const int r = t >> 4, c0 = (t & 15) * 8;
        const float* src = x + ((size_t)(b * NN + n0 + r)) * HD + c0;
        *(float4*)&xs[r][c0]     = *(const float4*)src;
        *(float4*)&xs[r][c0 + 4] = *(const float4*)(src + 4);
    }
    __syncthreads();
    const int nl = t & 15;
    const int h0 = (t >> 4) * 8;
    float s[8] = {0.f,0.f,0.f,0.f,0.f,0.f,0.f,0.f};
#pragma unroll 4
    for (int k = 0; k < HD; ++k) {
        const float xv = xs[nl][k];
        const float* wr = W + k * HD + h0;
        float4 wa = *(const float4*)wr;
        float4 wb = *(const float4*)(wr + 4);
        s[0] += xv * wa.x; s[1] += xv * wa.y; s[2] += xv * wa.z; s[3] += xv * wa.w;
        s[4] += xv * wb.x; s[5] += xv * wb.y; s[6] += xv * wb.z; s[7] += xv * wb.w;
    }
    const int n  = n0 + nl;
    const float nv = norm[b * NN + n];
    __hip_bfloat16* dst = snT2 + (size_t)b * NN * HD
                        + (size_t)(n >> 5) * (HD * 32) + (n & 31);
#pragma unroll
    for (int hb = 0; hb < 8; ++hb)
        dst[(h0 + hb) * 32] = __float2bfloat16(s[hb] * nv);
}

__device__ __forceinline__ bf16x8 cvt8(float4 a, float4 b) {
    bf16x8 r;
    r[0] = (__bf16)a.x; r[1] = (__bf16)a.y; r[2] = (__bf16)a.z; r[3] = (__bf16)a.w;
    r[4] = (__bf16)b.x; r[5] = (__bf16)b.y; r[6] = (__bf16)b.z; r[7] = (__bf16)b.w;
    return r;
}

// async global->LDS, 16 B per lane (dest = wave-uniform base + lane*16)
__device__ __forceinline__ void gload_lds16(const float* g, void* l) {
    __builtin_amdgcn_global_load_lds(
        (const __attribute__((address_space(1))) void*)g,
        (__attribute__((address_space(3))) void*)l, 16, 0, 0);
}

// ---- Kernel 3: out = elu( norm_m * (adj[b] @ support_norm^T) + bias ) -------
// Clean blocks/CU experiment at constant traffic: R17's exact tile geometry
// (BM=64, BK=128 fp32, 32 KB tiles, 64 steps, both-sides XOR swizzle,
// panel-major coalesced B) repackaged as 256-thread blocks with 2 LDS buffers
// (64 KB) and syncthreads pacing -> 2 INDEPENDENT barrier domains per CU
// (8 waves/CU total, same as R17's single 8-wave domain). Each wave owns all
// 64 m-rows x one 32-h slice: acc[mh][mt][ht] = 32 VGPR. When one block
// drains at its barrier, the partner block's waves keep the HBM queue fed.
__global__ __launch_bounds__(256, 2) void k_gemm20(const float* __restrict__ adj,
                                                   const __hip_bfloat16* __restrict__ snT2,
                                                   const float* __restrict__ norm,
                                                   const float* __restrict__ bias,
                                                   float* __restrict__ out) {
    const int b    = blockIdx.y;
    const int swz  = (blockIdx.x & 7) * 16 + (blockIdx.x >> 3);   // XCD-bijective (128 = 8x16)
    const int m0   = swz * BM;
    const int t    = threadIdx.x;
    const int w    = t >> 6;               // 0..3, h-slice owner (h0 = w*32)
    const int lane = t & 63;
    const int fr   = lane & 15;
    const int g    = lane >> 4;
    const int xr   = fr & 7;

    const float* adjB = adj + (size_t)b * NN * NN;
    const __hip_bfloat16* snB = snT2 + (size_t)b * NN * HD;

    __shared__ __align__(16) char Abuf[2][BM * BK * 4];   // 2 x 32 KB

    // staging: 2048 granules of 16 B (64 rows x 32); thread call c covers
    // fg = c*256 + t; row = fg>>5, slot = (fg&31)^(row&7) (both-sides XOR).
    const float* sptr[8];
#pragma unroll
    for (int c = 0; c < 8; ++c) {
        const int fg   = c * 256 + t;
        const int row  = fg >> 5;
        const int slot = (fg & 31) ^ (row & 7);
        sptr[c] = adjB + (size_t)(m0 + row) * NN + slot * 4;
    }

    // B base: panel-major; lane chunk = (w*32 + ht*16 + fr)*32 + g*8
    const __hip_bfloat16* bp0 = snB + (size_t)(w * 32 + fr) * 32 + g * 8;
    const __hip_bfloat16* bp1 = bp0 + 16 * 32;

    f32x4 acc[2][2][2] = {};   // [mh][mt][ht]

    // ---- prologue: stage step 0 into buf 0 ----
#pragma unroll
    for (int c = 0; c < 8; ++c)
        gload_lds16(sptr[c], &Abuf[0][c * 4096 + w * 1024]);

#pragma unroll 1
    for (int s = 0; s < NSTEP; ++s) {
        __syncthreads();               // buf[s&1] staged; prev-step reads done
        const char* lb = Abuf[s & 1];

        // B fragments for this step (issued before staging: their RAW waits
        // leave the stage queue in flight)
        bf16x8 Bf[2][4];
#pragma unroll
        for (int ks = 0; ks < 4; ++ks) {
            const size_t kp = (size_t)(s * 4 + ks) * (HD * 32);
            Bf[0][ks] = *(const bf16x8*)(bp0 + kp);
            Bf[1][ks] = *(const bf16x8*)(bp1 + kp);
        }

        // stage next adj tile into the other buffer
        if (s + 1 < NSTEP) {
            char* nb = Abuf[(s + 1) & 1];
#pragma unroll
            for (int c = 0; c < 8; ++c)
                gload_lds16(sptr[c] + (s + 1) * BK, &nb[c * 4096 + w * 1024]);
        }

        // compute from buf[s&1]
#pragma unroll
        for (int mh = 0; mh < 2; ++mh)
#pragma unroll
            for (int mt = 0; mt < 2; ++mt) {
                const char* rbase = lb + (mh * 32 + mt * 16 + fr) * 512;
#pragma unroll
                for (int ks = 0; ks < 4; ++ks) {
                    float4 fa = *(const float4*)(rbase + ((ks * 8 + ((g * 2 + 0) ^ xr)) << 4));
                    float4 fb = *(const float4*)(rbase + ((ks * 8 + ((g * 2 + 1) ^ xr)) << 4));
                    bf16x8 af = cvt8(fa, fb);
                    acc[mh][mt][0] = __builtin_amdgcn_mfma_f32_16x16x32_bf16(af, Bf[0][ks], acc[mh][mt][0], 0, 0, 0);
                    acc[mh][mt][1] = __builtin_amdgcn_mfma_f32_16x16x32_bf16(af, Bf[1][ks], acc[mh][mt][1], 0, 0, 0);
                }
            }
    }

    // ---- fused epilogue: *norm_m + bias, elu ----
    const float* normB = norm + b * NN + m0;
    float* outB = out + ((size_t)b * NN + m0) * HD;
#pragma unroll
    for (int mh = 0; mh < 2; ++mh)
#pragma unroll
        for (int mt = 0; mt < 2; ++mt)
#pragma unroll
            for (int ht = 0; ht < 2; ++ht) {
                const int h  = w * 32 + ht * 16 + fr;
                const float bv = bias[h];
#pragma unroll
                for (int j = 0; j < 4; ++j) {
                    const int r = mh * 32 + mt * 16 + g * 4 + j;
                    float v = acc[mh][mt][ht][j] * normB[r] + bv;
                    v = v > 0.f ? v : expm1f(v);
                    outB[(size_t)r * HD + h] = v;
                }
            }
}

extern "C" void kernel_launch(void* const* d_in, const int* in_sizes, int n_in,
                              void* d_out, int out_size, void* d_ws, size_t ws_size,
                              hipStream_t stream) {
    (void)in_sizes; (void)n_in; (void)out_size; (void)ws_size;
    const float* x    = (const float*)d_in[0];
    const float* adj  = (const float*)d_in[1];
    const float* W    = (const float*)d_in[2];
    const float* bias = (const float*)d_in[3];
    float* out = (float*)d_out;

    float* norm = (float*)d_ws;                                     // 16384 f32
    __hip_bfloat16* snT2 = (__hip_bfloat16*)((char*)d_ws + 65536);  // 4 MB, panel-major

    k_degree <<<dim3(NB * NN / 4),  dim3(256), 0, stream>>>(adj, norm);
    k_support<<<dim3(NB * NN / 16), dim3(256), 0, stream>>>(x, W, norm, snT2);
    k_gemm20 <<<dim3(NN / BM, NB),  dim3(256), 0, stream>>>(adj, snT2, norm, bias, out);
}

// Round 21
// 258.349 us; speedup vs baseline: 1.0308x; 1.0308x over previous
//
#include <hip/hip_runtime.h>
#include <hip/hip_bf16.h>
#include <math.h>

#define NN 8192
#define HD 128
#define NB 2
#define EPSF 1e-6f
#define BM 64
#define BK 128                // fp32 K per step (tile = 64x128x4B = 32 KB)
#define NSTEP (NN / BK)       // 64

typedef __attribute__((ext_vector_type(8))) __bf16 bf16x8;
typedef __attribute__((ext_vector_type(4))) float f32x4;

// ---------------- Kernel 1: norm = rsqrt(sum|adj_row| + eps) -----------------
__global__ __launch_bounds__(256) void k_degree(const float* __restrict__ adj,
                                                float* __restrict__ norm) {
    const int row  = blockIdx.x * 4 + (threadIdx.x >> 6);
    const int lane = threadIdx.x & 63;
    const float4* p = (const float4*)(adj + (size_t)row * NN);
    float s = 0.f;
#pragma unroll
    for (int i = 0; i < 32; ++i) {
        float4 v = p[(size_t)i * 64 + lane];
        s += fabsf(v.x) + fabsf(v.y) + fabsf(v.z) + fabsf(v.w);
    }
#pragma unroll
    for (int off = 32; off > 0; off >>= 1) s += __shfl_down(s, off);
    if (lane == 0) norm[row] = rsqrtf(s + EPSF);
}

// --- Kernel 2: snT2[b][n/32][h][n&31] = bf16( (x@W)[b][n][h] * norm[b][n] ) --
// K-panel-major layout (R15-verified): gemm B loads are 1 KB/wave contiguous.
__global__ __launch_bounds__(256) void k_support(const float* __restrict__ x,
                                                 const float* __restrict__ W,
                                                 const float* __restrict__ norm,
                                                 __hip_bfloat16* __restrict__ snT2) {
    const int b  = blockIdx.x >> 9;
    const int n0 = (blockIdx.x & 511) * 16;
    __shared__ float xs[16][132];
    const int t = threadIdx.x;
    {
        const int r = t >> 4, c0 = (t & 15) * 8;
        const float* src = x + ((size_t)(b * NN + n0 + r)) * HD + c0;
        *(float4*)&xs[r][c0]     = *(const float4*)src;
        *(float4*)&xs[r][c0 + 4] = *(const float4*)(src + 4);
    }
    __syncthreads();
    const int nl = t & 15;
    const int h0 = (t >> 4) * 8;
    float s[8] = {0.f,0.f,0.f,0.f,0.f,0.f,0.f,0.f};
#pragma unroll 4
    for (int k = 0; k < HD; ++k) {
        const float xv = xs[nl][k];
        const float* wr = W + k * HD + h0;
        float4 wa = *(const float4*)wr;
        float4 wb = *(const float4*)(wr + 4);
        s[0] += xv * wa.x; s[1] += xv * wa.y; s[2] += xv * wa.z; s[3] += xv * wa.w;
        s[4] += xv * wb.x; s[5] += xv * wb.y; s[6] += xv * wb.z; s[7] += xv * wb.w;
    }
    const int n  = n0 + nl;
    const float nv = norm[b * NN + n];
    __hip_bfloat16* dst = snT2 + (size_t)b * NN * HD
                        + (size_t)(n >> 5) * (HD * 32) + (n & 31);
#pragma unroll
    for (int hb = 0; hb < 8; ++hb)
        dst[(h0 + hb) * 32] = __float2bfloat16(s[hb] * nv);
}

__device__ __forceinline__ bf16x8 cvt8(float4 a, float4 b) {
    bf16x8 r;
    r[0] = (__bf16)a.x; r[1] = (__bf16)a.y; r[2] = (__bf16)a.z; r[3] = (__bf16)a.w;
    r[4] = (__bf16)b.x; r[5] = (__bf16)b.y; r[6] = (__bf16)b.z; r[7] = (__bf16)b.w;
    return r;
}

// async global->LDS, 16 B per lane (dest = wave-uniform base + lane*16)
__device__ __forceinline__ void gload_lds16(const float* g, void* l) {
    __builtin_amdgcn_global_load_lds(
        (const __attribute__((address_space(1))) void*)g,
        (__attribute__((address_space(3))) void*)l, 16, 0, 0);
}

// ---- Kernel 3: out = elu( norm_m * (adj[b] @ support_norm^T) + bias ) -------
// R17 (best known, 133 us gemm) with STAGE-AHEAD-3: each tile gets ~3 steps
// from issue to first use instead of ~1 (HBM queuing slack -- the remaining
// untested variable). STAGE moved AFTER the barrier (R10-verified ordering):
// st(j+3) overwrites buf[(j-1)&3] whose readers finished before this barrier;
// its own readers (COMPUTE(j+3)) are gated by the WAITN at H(j+3), where
// st(j+3) is older than the newest 12. Steady-state outstanding at WAITN:
// B(j+1)[8] + st(j+2)[4] = 12 newest -> WAITN(12) retires B(j), st(j+1),
// st(j). Prologue: LOADB(BfA,0) BEFORE stages (else WAITN(12) would leave a
// partial B bank in flight). Tail waits: 12/12/8/0. All else = R17.
__global__ __launch_bounds__(512, 2) void k_gemm21(const float* __restrict__ adj,
                                                   const __hip_bfloat16* __restrict__ snT2,
                                                   const float* __restrict__ norm,
                                                   const float* __restrict__ bias,
                                                   float* __restrict__ out) {
    const int b    = blockIdx.y;
    const int swz  = (blockIdx.x & 7) * 16 + (blockIdx.x >> 3);   // XCD-bijective (128 = 8x16)
    const int m0   = swz * BM;
    const int w    = threadIdx.x >> 6;     // 0..7
    const int mh   = w & 1;                // m-half owner (32 rows)
    const int hs   = w >> 1;               // h-slice owner (32 h)
    const int lane = threadIdx.x & 63;
    const int fr   = lane & 15;
    const int g    = lane >> 4;
    const int xr   = fr & 7;

    const float* adjB = adj + (size_t)b * NN * NN;
    const __hip_bfloat16* snB = snT2 + (size_t)b * NN * HD;

    __shared__ __align__(16) char Abuf[4][BM * BK * 4];   // 4 x 32 KB

    // staging: thread call c covers 16B-granule fg = c*512 + w*64 + lane
    // (2048 granules = 64 rows x 32); row = fg>>5, slot = (fg&31)^(row&7).
    const float* sptr[4];
#pragma unroll
    for (int c = 0; c < 4; ++c) {
        const int fg   = c * 512 + w * 64 + lane;
        const int row  = fg >> 5;
        const int gsrc = (fg & 31) ^ (row & 7);
        sptr[c] = adjB + (size_t)(m0 + row) * NN + gsrc * 4;
    }

    // B base: panel-major; lane chunk = (hs*32 + ht*16 + fr)*32 + g*8
    const __hip_bfloat16* bp0 = snB + (size_t)(hs * 32 + fr) * 32 + g * 8;
    const __hip_bfloat16* bp1 = bp0 + 16 * 32;

    f32x4 acc[2][2] = {};   // [m-tile within half][h-tile]
    bf16x8 BfA[2][4], BfB[2][4];

#define STAGE(idx) do {                                                       \
        char* nb_ = Abuf[(idx) & 3];                                          \
        _Pragma("unroll")                                                     \
        for (int c = 0; c < 4; ++c)                                           \
            gload_lds16(sptr[c] + (idx) * BK, &nb_[c * 8192 + w * 1024]);     \
    } while (0)
#define LOADB(BX, idx) do {                                                   \
        _Pragma("unroll")                                                     \
        for (int ks = 0; ks < 4; ++ks) {                                      \
            const size_t kp_ = (size_t)((idx) * 4 + ks) * (HD * 32);          \
            BX[0][ks] = *(const bf16x8*)(bp0 + kp_);                          \
            BX[1][ks] = *(const bf16x8*)(bp1 + kp_);                          \
        }                                                                     \
    } while (0)
#define WAITN(n) asm volatile("s_waitcnt vmcnt(" #n ")" ::: "memory")
#define SB() __builtin_amdgcn_sched_barrier(0)
#define BAR() do { __builtin_amdgcn_s_barrier(); SB(); } while (0)
#define COMPUTE(kidx, BX) do {                                                \
        const char* lb_ = Abuf[(kidx) & 3];                                   \
        _Pragma("unroll")                                                     \
        for (int mt = 0; mt < 2; ++mt) {                                      \
            const char* rbase_ = lb_ + (mh * 32 + mt * 16 + fr) * 512;        \
            _Pragma("unroll")                                                 \
            for (int ks = 0; ks < 4; ++ks) {                                  \
                float4 fa_ = *(const float4*)(rbase_ + ((ks * 8 + ((g * 2 + 0) ^ xr)) << 4)); \
                float4 fb_ = *(const float4*)(rbase_ + ((ks * 8 + ((g * 2 + 1) ^ xr)) << 4)); \
                bf16x8 af_ = cvt8(fa_, fb_);                                  \
                acc[mt][0] = __builtin_amdgcn_mfma_f32_16x16x32_bf16(af_, BX[0][ks], acc[mt][0], 0, 0, 0); \
                acc[mt][1] = __builtin_amdgcn_mfma_f32_16x16x32_bf16(af_, BX[1][ks], acc[mt][1], 0, 0, 0); \
            }                                                                 \
        }                                                                     \
    } while (0)

    // ---- prologue: B(0) first (bank must be older than the 12-newest), then
    // stages 0..2 ----
    LOADB(BfA, 0);
    STAGE(0);
    STAGE(1);
    STAGE(2);

    // ---- main loop: halves j = k (even) and k+1; stage j+3 after barrier ----
#pragma unroll 1
    for (int k = 0; k < NSTEP - 4; k += 2) {
        LOADB(BfB, k + 1);
        WAITN(12); BAR();
        STAGE(k + 3); SB();
        COMPUTE(k, BfA);

        LOADB(BfA, k + 2);
        WAITN(12); BAR();
        STAGE(k + 4); SB();
        COMPUTE(k + 1, BfB);
    }

    // ---- tail: j = 60, 61, 62, 63 ----
    LOADB(BfB, NSTEP - 3);
    WAITN(12); BAR();
    STAGE(NSTEP - 1); SB();
    COMPUTE(NSTEP - 4, BfA);

    LOADB(BfA, NSTEP - 2);
    WAITN(12); BAR();
    COMPUTE(NSTEP - 3, BfB);

    LOADB(BfB, NSTEP - 1);
    WAITN(8); BAR();
    COMPUTE(NSTEP - 2, BfA);

    WAITN(0); BAR();
    COMPUTE(NSTEP - 1, BfB);

#undef STAGE
#undef LOADB
#undef WAITN
#undef SB
#undef BAR
#undef COMPUTE

    // ---- fused epilogue: *norm_m + bias, elu ----
    const float* normB = norm + b * NN + m0;
    float* outB = out + ((size_t)b * NN + m0) * HD;
#pragma unroll
    for (int mt = 0; mt < 2; ++mt)
#pragma unroll
        for (int ht = 0; ht < 2; ++ht) {
            const int h  = hs * 32 + ht * 16 + fr;
            const float bv = bias[h];
#pragma unroll
            for (int j = 0; j < 4; ++j) {
                const int r = mh * 32 + mt * 16 + g * 4 + j;
                float v = acc[mt][ht][j] * normB[r] + bv;
                v = v > 0.f ? v : expm1f(v);
                outB[(size_t)r * HD + h] = v;
            }
        }
}

extern "C" void kernel_launch(void* const* d_in, const int* in_sizes, int n_in,
                              void* d_out, int out_size, void* d_ws, size_t ws_size,
                              hipStream_t stream) {
    (void)in_sizes; (void)n_in; (void)out_size; (void)ws_size;
    const float* x    = (const float*)d_in[0];
    const float* adj  = (const float*)d_in[1];
    const float* W    = (const float*)d_in[2];
    const float* bias = (const float*)d_in[3];
    float* out = (float*)d_out;

    float* norm = (float*)d_ws;                                     // 16384 f32
    __hip_bfloat16* snT2 = (__hip_bfloat16*)((char*)d_ws + 65536);  // 4 MB, panel-major

    k_degree <<<dim3(NB * NN / 4),  dim3(256), 0, stream>>>(adj, norm);
    k_support<<<dim3(NB * NN / 16), dim3(256), 0, stream>>>(x, W, norm, snT2);
    k_gemm21 <<<dim3(NN / BM, NB),  dim3(512), 0, stream>>>(adj, snT2, norm, bias, out);
}

// Round 22
// 236.231 us; speedup vs baseline: 1.1273x; 1.0936x over previous
//
#include <hip/hip_runtime.h>
#include <hip/hip_bf16.h>
#include <math.h>

#define NN 8192
#define HD 128
#define NB 2
#define EPSF 1e-6f
#define BM 64
#define BK 128
#define NSTEP (NN / BK)   // 64

typedef __attribute__((ext_vector_type(8))) __bf16 bf16x8;
typedef __attribute__((ext_vector_type(4))) float f32x4;

// ---------------- Kernel 1: norm = rsqrt(sum|adj_row| + eps) -----------------
__global__ __launch_bounds__(256) void k_degree(const float* __restrict__ adj,
                                                float* __restrict__ norm) {
    const int row  = blockIdx.x * 4 + (threadIdx.x >> 6);
    const int lane = threadIdx.x & 63;
    const float4* p = (const float4*)(adj + (size_t)row * NN);
    float s = 0.f;
#pragma unroll
    for (int i = 0; i < 32; ++i) {
        float4 v = p[(size_t)i * 64 + lane];
        s += fabsf(v.x) + fabsf(v.y) + fabsf(v.z) + fabsf(v.w);
    }
#pragma unroll
    for (int off = 32; off > 0; off >>= 1) s += __shfl_down(s, off);
    if (lane == 0) norm[row] = rsqrtf(s + EPSF);
}

// --- Kernel 2: snT2[b][n/32][h][n&31] = bf16( (x@W)[b][n][h] * norm[b][n] ) --
// K-panel-major layout (R15-verified): gemm B loads are 1 KB/wave contiguous.
__global__ __launch_bounds__(256) void k_support(const float* __restrict__ x,
                                                 const float* __restrict__ W,
                                                 const float* __restrict__ norm,
                                                 __hip_bfloat16* __restrict__ snT2) {
    const int b  = blockIdx.x >> 9;
    const int n0 = (blockIdx.x & 511) * 16;
    __shared__ float xs[16][132];
    const int t = threadIdx.x;
    {
        const int r = t >> 4, c0 = (t & 15) * 8;
        const float* src = x + ((size_t)(b * NN + n0 + r)) * HD + c0;
        *(float4*)&xs[r][c0]     = *(const float4*)src;
        *(float4*)&xs[r][c0 + 4] = *(const float4*)(src + 4);
    }
    __syncthreads();
    const int nl = t & 15;
    const int h0 = (t >> 4) * 8;
    float s[8] = {0.f,0.f,0.f,0.f,0.f,0.f,0.f,0.f};
#pragma unroll 4
    for (int k = 0; k < HD; ++k) {
        const float xv = xs[nl][k];
        const float* wr = W + k * HD + h0;
        float4 wa = *(const float4*)wr;
        float4 wb = *(const float4*)(wr + 4);
        s[0] += xv * wa.x; s[1] += xv * wa.y; s[2] += xv * wa.z; s[3] += xv * wa.w;
        s[4] += xv * wb.x; s[5] += xv * wb.y; s[6] += xv * wb.z; s[7] += xv * wb.w;
    }
    const int n  = n0 + nl;
    const float nv = norm[b * NN + n];
    __hip_bfloat16* dst = snT2 + (size_t)b * NN * HD
                        + (size_t)(n >> 5) * (HD * 32) + (n & 31);
#pragma unroll
    for (int hb = 0; hb < 8; ++hb)
        dst[(h0 + hb) * 32] = __float2bfloat16(s[hb] * nv);
}

__device__ __forceinline__ bf16x8 cvt8(float4 a, float4 b) {
    bf16x8 r;
    r[0] = (__bf16)a.x; r[1] = (__bf16)a.y; r[2] = (__bf16)a.z; r[3] = (__bf16)a.w;
    r[4] = (__bf16)b.x; r[5] = (__bf16)b.y; r[6] = (__bf16)b.z; r[7] = (__bf16)b.w;
    return r;
}

// async global->LDS, 16 B per lane (dest = wave-uniform base + lane*16)
__device__ __forceinline__ void gload_lds16(const float* g, void* l) {
    __builtin_amdgcn_global_load_lds(
        (const __attribute__((address_space(1))) void*)g,
        (__attribute__((address_space(3))) void*)l, 16, 0, 0);
}

// ---- Kernel 3: out = elu( norm_m * (adj[b] @ support_norm^T) + bias ) -------
// R17 verbatim (best verified: gemm ~133 us, total 236.2). BM=64 counted-vmcnt
// pipeline: 512 threads = 8 waves = 2 m-halves x 4 h-slices; 4 x 32 KB LDS
// buffers; stage-ahead-2; B one step ahead in ping-pong banks. Per half-iter:
// B(k+1)[8] + stage(k+2)[4] -> WAITN(16) retires st(k) and B(k). Both-sides
// XOR swizzle + panel-major coalesced B (verified absmax 0.015625, 7 rounds).
__global__ __launch_bounds__(512, 2) void k_gemm17(const float* __restrict__ adj,
                                                   const __hip_bfloat16* __restrict__ snT2,
                                                   const float* __restrict__ norm,
                                                   const float* __restrict__ bias,
                                                   float* __restrict__ out) {
    const int b    = blockIdx.y;
    const int swz  = (blockIdx.x & 7) * 16 + (blockIdx.x >> 3);   // XCD-bijective (128 = 8x16)
    const int m0   = swz * BM;
    const int w    = threadIdx.x >> 6;     // 0..7
    const int mh   = w & 1;                // m-half owner (32 rows)
    const int hs   = w >> 1;               // h-slice owner (32 h)
    const int lane = threadIdx.x & 63;
    const int fr   = lane & 15;
    const int g    = lane >> 4;
    const int xr   = fr & 7;

    const float* adjB = adj + (size_t)b * NN * NN;
    const __hip_bfloat16* snB = snT2 + (size_t)b * NN * HD;

    __shared__ __align__(16) char Abuf[4][BM * BK * 4];   // 4 x 32 KB

    // staging: thread call c covers 16B-granule fg = c*512 + w*64 + lane
    // (2048 granules = 64 rows x 32); row = fg>>5, slot = (fg&31)^(row&7).
    const float* sptr[4];
#pragma unroll
    for (int c = 0; c < 4; ++c) {
        const int fg   = c * 512 + w * 64 + lane;
        const int row  = fg >> 5;
        const int gsrc = (fg & 31) ^ (row & 7);
        sptr[c] = adjB + (size_t)(m0 + row) * NN + gsrc * 4;
    }

    // B base: panel-major; lane chunk = (hs*32 + ht*16 + fr)*32 + g*8
    const __hip_bfloat16* bp0 = snB + (size_t)(hs * 32 + fr) * 32 + g * 8;
    const __hip_bfloat16* bp1 = bp0 + 16 * 32;

    f32x4 acc[2][2] = {};   // [m-tile within half][h-tile]
    bf16x8 BfA[2][4], BfB[2][4];

#define STAGE(idx) do {                                                       \
        char* nb_ = Abuf[(idx) & 3];                                          \
        _Pragma("unroll")                                                     \
        for (int c = 0; c < 4; ++c)                                           \
            gload_lds16(sptr[c] + (idx) * BK, &nb_[c * 8192 + w * 1024]);     \
    } while (0)
#define LOADB(BX, idx) do {                                                   \
        _Pragma("unroll")                                                     \
        for (int ks = 0; ks < 4; ++ks) {                                      \
            const size_t kp_ = (size_t)((idx) * 4 + ks) * (HD * 32);          \
            BX[0][ks] = *(const bf16x8*)(bp0 + kp_);                          \
            BX[1][ks] = *(const bf16x8*)(bp1 + kp_);                          \
        }                                                                     \
    } while (0)
#define WAITN(n) asm volatile("s_waitcnt vmcnt(" #n ")" ::: "memory")
#define BAR() do { __builtin_amdgcn_s_barrier();                              \
                   __builtin_amdgcn_sched_barrier(0); } while (0)
#define COMPUTE(kidx, BX) do {                                                \
        const char* lb_ = Abuf[(kidx) & 3];                                   \
        _Pragma("unroll")                                                     \
        for (int mt = 0; mt < 2; ++mt) {                                      \
            const char* rbase_ = lb_ + (mh * 32 + mt * 16 + fr) * 512;        \
            _Pragma("unroll")                                                 \
            for (int ks = 0; ks < 4; ++ks) {                                  \
                float4 fa_ = *(const float4*)(rbase_ + ((ks * 8 + ((g * 2 + 0) ^ xr)) << 4)); \
                float4 fb_ = *(const float4*)(rbase_ + ((ks * 8 + ((g * 2 + 1) ^ xr)) << 4)); \
                bf16x8 af_ = cvt8(fa_, fb_);                                  \
                acc[mt][0] = __builtin_amdgcn_mfma_f32_16x16x32_bf16(af_, BX[0][ks], acc[mt][0], 0, 0, 0); \
                acc[mt][1] = __builtin_amdgcn_mfma_f32_16x16x32_bf16(af_, BX[1][ks], acc[mt][1], 0, 0, 0); \
            }                                                                 \
        }                                                                     \
    } while (0)

    // ---- prologue: stage 0,1; B(0) into bank A ----
    STAGE(0);
    STAGE(1);
    LOADB(BfA, 0);

    // ---- main loop ----
#pragma unroll 1
    for (int k = 0; k < NSTEP - 3; k += 2) {
        LOADB(BfB, k + 1);
        STAGE(k + 2);
        WAITN(16); BAR();
        COMPUTE(k, BfA);

        LOADB(BfA, k + 2);
        STAGE(k + 3);
        WAITN(16); BAR();
        COMPUTE(k + 1, BfB);
    }

    // ---- tail ----
    LOADB(BfB, NSTEP - 1);
    WAITN(0); BAR();
    COMPUTE(NSTEP - 2, BfA);

    WAITN(0); BAR();
    COMPUTE(NSTEP - 1, BfB);

#undef STAGE
#undef LOADB
#undef WAITN
#undef BAR
#undef COMPUTE

    // ---- fused epilogue: *norm_m + bias, elu ----
    const float* normB = norm + b * NN + m0;
    float* outB = out + ((size_t)b * NN + m0) * HD;
#pragma unroll
    for (int mt = 0; mt < 2; ++mt)
#pragma unroll
        for (int ht = 0; ht < 2; ++ht) {
            const int h  = hs * 32 + ht * 16 + fr;
            const float bv = bias[h];
#pragma unroll
            for (int j = 0; j < 4; ++j) {
                const int r = mh * 32 + mt * 16 + g * 4 + j;
                float v = acc[mt][ht][j] * normB[r] + bv;
                v = v > 0.f ? v : expm1f(v);
                outB[(size_t)r * HD + h] = v;
            }
        }
}

extern "C" void kernel_launch(void* const* d_in, const int* in_sizes, int n_in,
                              void* d_out, int out_size, void* d_ws, size_t ws_size,
                              hipStream_t stream) {
    (void)in_sizes; (void)n_in; (void)out_size; (void)ws_size;
    const float* x    = (const float*)d_in[0];
    const float* adj  = (const float*)d_in[1];
    const float* W    = (const float*)d_in[2];
    const float* bias = (const float*)d_in[3];
    float* out = (float*)d_out;

    float* norm = (float*)d_ws;                                     // 16384 f32
    __hip_bfloat16* snT2 = (__hip_bfloat16*)((char*)d_ws + 65536);  // 4 MB, panel-major

    k_degree <<<dim3(NB * NN / 4),  dim3(256), 0, stream>>>(adj, norm);
    k_support<<<dim3(NB * NN / 16), dim3(256), 0, stream>>>(x, W, norm, snT2);
    k_gemm17 <<<dim3(NN / BM, NB),  dim3(512), 0, stream>>>(adj, snT2, norm, bias, out);
}

// Round 23
// 230.894 us; speedup vs baseline: 1.1534x; 1.0231x over previous
//
#include <hip/hip_runtime.h>
#include <hip/hip_bf16.h>
#include <math.h>

#define NN 8192
#define HD 128
#define NB 2
#define EPSF 1e-6f
#define BM 64
#define BK 128
#define NSTEP (NN / BK)   // 64

typedef __attribute__((ext_vector_type(8))) __bf16 bf16x8;
typedef __attribute__((ext_vector_type(4))) float f32x4;

// ---------------- Kernel 1: norm = rsqrt(sum|adj_row| + eps) -----------------
// NON-TEMPORAL loads: adj must not be installed in L3/L2 by this pass, so the
// gemm's B stream (snT2, served by L2/L3) does not contend with a polluted
// L3 -- the gemm then pulls A from HBM and B from cache IN PARALLEL instead
// of both through one saturated L3 port (the R22 diagnosis: gemm moves
// ~1.05 GB through L3 at ~8 TB/s = its ceiling).
__global__ __launch_bounds__(256) void k_degree(const float* __restrict__ adj,
                                                float* __restrict__ norm) {
    const int row  = blockIdx.x * 4 + (threadIdx.x >> 6);
    const int lane = threadIdx.x & 63;
    const f32x4* p = (const f32x4*)(adj + (size_t)row * NN);
    float s = 0.f;
#pragma unroll
    for (int i = 0; i < 32; ++i) {
        f32x4 v = __builtin_nontemporal_load(&p[(size_t)i * 64 + lane]);
        s += fabsf(v[0]) + fabsf(v[1]) + fabsf(v[2]) + fabsf(v[3]);
    }
#pragma unroll
    for (int off = 32; off > 0; off >>= 1) s += __shfl_down(s, off);
    if (lane == 0) norm[row] = rsqrtf(s + EPSF);
}

// --- Kernel 2: snT2[b][n/32][h][n&31] = bf16( (x@W)[b][n][h] * norm[b][n] ) --
// K-panel-major layout (R15-verified): gemm B loads are 1 KB/wave contiguous.
__global__ __launch_bounds__(256) void k_support(const float* __restrict__ x,
                                                 const float* __restrict__ W,
                                                 const float* __restrict__ norm,
                                                 __hip_bfloat16* __restrict__ snT2) {
    const int b  = blockIdx.x >> 9;
    const int n0 = (blockIdx.x & 511) * 16;
    __shared__ float xs[16][132];
    const int t = threadIdx.x;
    {
        const int r = t >> 4, c0 = (t & 15) * 8;
        const float* src = x + ((size_t)(b * NN + n0 + r)) * HD + c0;
        *(float4*)&xs[r][c0]     = *(const float4*)src;
        *(float4*)&xs[r][c0 + 4] = *(const float4*)(src + 4);
    }
    __syncthreads();
    const int nl = t & 15;
    const int h0 = (t >> 4) * 8;
    float s[8] = {0.f,0.f,0.f,0.f,0.f,0.f,0.f,0.f};
#pragma unroll 4
    for (int k = 0; k < HD; ++k) {
        const float xv = xs[nl][k];
        const float* wr = W + k * HD + h0;
        float4 wa = *(const float4*)wr;
        float4 wb = *(const float4*)(wr + 4);
        s[0] += xv * wa.x; s[1] += xv * wa.y; s[2] += xv * wa.z; s[3] += xv * wa.w;
        s[4] += xv * wb.x; s[5] += xv * wb.y; s[6] += xv * wb.z; s[7] += xv * wb.w;
    }
    const int n  = n0 + nl;
    const float nv = norm[b * NN + n];
    __hip_bfloat16* dst = snT2 + (size_t)b * NN * HD
                        + (size_t)(n >> 5) * (HD * 32) + (n & 31);
#pragma unroll
    for (int hb = 0; hb < 8; ++hb)
        dst[(h0 + hb) * 32] = __float2bfloat16(s[hb] * nv);
}

__device__ __forceinline__ bf16x8 cvt8(float4 a, float4 b) {
    bf16x8 r;
    r[0] = (__bf16)a.x; r[1] = (__bf16)a.y; r[2] = (__bf16)a.z; r[3] = (__bf16)a.w;
    r[4] = (__bf16)b.x; r[5] = (__bf16)b.y; r[6] = (__bf16)b.z; r[7] = (__bf16)b.w;
    return r;
}

// async global->LDS, 16 B per lane (dest = wave-uniform base + lane*16)
__device__ __forceinline__ void gload_lds16(const float* g, void* l) {
    __builtin_amdgcn_global_load_lds(
        (const __attribute__((address_space(1))) void*)g,
        (__attribute__((address_space(3))) void*)l, 16, 0, 0);
}

// ---- Kernel 3: out = elu( norm_m * (adj[b] @ support_norm^T) + bias ) -------
// R17 verbatim (best verified: gemm ~133 us, total 236.2). BM=64 counted-vmcnt
// pipeline: 512 threads = 8 waves = 2 m-halves x 4 h-slices; 4 x 32 KB LDS
// buffers; stage-ahead-2; B one step ahead in ping-pong banks. Per half-iter:
// B(k+1)[8] + stage(k+2)[4] -> WAITN(16) retires st(k) and B(k). Both-sides
// XOR swizzle + panel-major coalesced B (verified absmax 0.015625, 8 rounds).
__global__ __launch_bounds__(512, 2) void k_gemm17(const float* __restrict__ adj,
                                                   const __hip_bfloat16* __restrict__ snT2,
                                                   const float* __restrict__ norm,
                                                   const float* __restrict__ bias,
                                                   float* __restrict__ out) {
    const int b    = blockIdx.y;
    const int swz  = (blockIdx.x & 7) * 16 + (blockIdx.x >> 3);   // XCD-bijective (128 = 8x16)
    const int m0   = swz * BM;
    const int w    = threadIdx.x >> 6;     // 0..7
    const int mh   = w & 1;                // m-half owner (32 rows)
    const int hs   = w >> 1;               // h-slice owner (32 h)
    const int lane = threadIdx.x & 63;
    const int fr   = lane & 15;
    const int g    = lane >> 4;
    const int xr   = fr & 7;

    const float* adjB = adj + (size_t)b * NN * NN;
    const __hip_bfloat16* snB = snT2 + (size_t)b * NN * HD;

    __shared__ __align__(16) char Abuf[4][BM * BK * 4];   // 4 x 32 KB

    // staging: thread call c covers 16B-granule fg = c*512 + w*64 + lane
    // (2048 granules = 64 rows x 32); row = fg>>5, slot = (fg&31)^(row&7).
    const float* sptr[4];
#pragma unroll
    for (int c = 0; c < 4; ++c) {
        const int fg   = c * 512 + w * 64 + lane;
        const int row  = fg >> 5;
        const int gsrc = (fg & 31) ^ (row & 7);
        sptr[c] = adjB + (size_t)(m0 + row) * NN + gsrc * 4;
    }

    // B base: panel-major; lane chunk = (hs*32 + ht*16 + fr)*32 + g*8
    const __hip_bfloat16* bp0 = snB + (size_t)(hs * 32 + fr) * 32 + g * 8;
    const __hip_bfloat16* bp1 = bp0 + 16 * 32;

    f32x4 acc[2][2] = {};   // [m-tile within half][h-tile]
    bf16x8 BfA[2][4], BfB[2][4];

#define STAGE(idx) do {                                                       \
        char* nb_ = Abuf[(idx) & 3];                                          \
        _Pragma("unroll")                                                     \
        for (int c = 0; c < 4; ++c)                                           \
            gload_lds16(sptr[c] + (idx) * BK, &nb_[c * 8192 + w * 1024]);     \
    } while (0)
#define LOADB(BX, idx) do {                                                   \
        _Pragma("unroll")                                                     \
        for (int ks = 0; ks < 4; ++ks) {                                      \
            const size_t kp_ = (size_t)((idx) * 4 + ks) * (HD * 32);          \
            BX[0][ks] = *(const bf16x8*)(bp0 + kp_);                          \
            BX[1][ks] = *(const bf16x8*)(bp1 + kp_);                          \
        }                                                                     \
    } while (0)
#define WAITN(n) asm volatile("s_waitcnt vmcnt(" #n ")" ::: "memory")
#define BAR() do { __builtin_amdgcn_s_barrier();                              \
                   __builtin_amdgcn_sched_barrier(0); } while (0)
#define COMPUTE(kidx, BX) do {                                                \
        const char* lb_ = Abuf[(kidx) & 3];                                   \
        _Pragma("unroll")                                                     \
        for (int mt = 0; mt < 2; ++mt) {                                      \
            const char* rbase_ = lb_ + (mh * 32 + mt * 16 + fr) * 512;        \
            _Pragma("unroll")                                                 \
            for (int ks = 0; ks < 4; ++ks) {                                  \
                float4 fa_ = *(const float4*)(rbase_ + ((ks * 8 + ((g * 2 + 0) ^ xr)) << 4)); \
                float4 fb_ = *(const float4*)(rbase_ + ((ks * 8 + ((g * 2 + 1) ^ xr)) << 4)); \
                bf16x8 af_ = cvt8(fa_, fb_);                                  \
                acc[mt][0] = __builtin_amdgcn_mfma_f32_16x16x32_bf16(af_, BX[0][ks], acc[mt][0], 0, 0, 0); \
                acc[mt][1] = __builtin_amdgcn_mfma_f32_16x16x32_bf16(af_, BX[1][ks], acc[mt][1], 0, 0, 0); \
            }                                                                 \
        }                                                                     \
    } while (0)

    // ---- prologue: stage 0,1; B(0) into bank A ----
    STAGE(0);
    STAGE(1);
    LOADB(BfA, 0);

    // ---- main loop ----
#pragma unroll 1
    for (int k = 0; k < NSTEP - 3; k += 2) {
        LOADB(BfB, k + 1);
        STAGE(k + 2);
        WAITN(16); BAR();
        COMPUTE(k, BfA);

        LOADB(BfA, k + 2);
        STAGE(k + 3);
        WAITN(16); BAR();
        COMPUTE(k + 1, BfB);
    }

    // ---- tail ----
    LOADB(BfB, NSTEP - 1);
    WAITN(0); BAR();
    COMPUTE(NSTEP - 2, BfA);

    WAITN(0); BAR();
    COMPUTE(NSTEP - 1, BfB);

#undef STAGE
#undef LOADB
#undef WAITN
#undef BAR
#undef COMPUTE

    // ---- fused epilogue: *norm_m + bias, elu ----
    const float* normB = norm + b * NN + m0;
    float* outB = out + ((size_t)b * NN + m0) * HD;
#pragma unroll
    for (int mt = 0; mt < 2; ++mt)
#pragma unroll
        for (int ht = 0; ht < 2; ++ht) {
            const int h  = hs * 32 + ht * 16 + fr;
            const float bv = bias[h];
#pragma unroll
            for (int j = 0; j < 4; ++j) {
                const int r = mh * 32 + mt * 16 + g * 4 + j;
                float v = acc[mt][ht][j] * normB[r] + bv;
                v = v > 0.f ? v : expm1f(v);
                outB[(size_t)r * HD + h] = v;
            }
        }
}

extern "C" void kernel_launch(void* const* d_in, const int* in_sizes, int n_in,
                              void* d_out, int out_size, void* d_ws, size_t ws_size,
                              hipStream_t stream) {
    (void)in_sizes; (void)n_in; (void)out_size; (void)ws_size;
    const float* x    = (const float*)d_in[0];
    const float* adj  = (const float*)d_in[1];
    const float* W    = (const float*)d_in[2];
    const float* bias = (const float*)d_in[3];
    float* out = (float*)d_out;

    float* norm = (float*)d_ws;                                     // 16384 f32
    __hip_bfloat16* snT2 = (__hip_bfloat16*)((char*)d_ws + 65536);  // 4 MB, panel-major

    k_degree <<<dim3(NB * NN / 4),  dim3(256), 0, stream>>>(adj, norm);
    k_support<<<dim3(NB * NN / 16), dim3(256), 0, stream>>>(x, W, norm, snT2);
    k_gemm17 <<<dim3(NN / BM, NB),  dim3(512), 0, stream>>>(adj, snT2, norm, bias, out);
}

// Round 24
// 228.755 us; speedup vs baseline: 1.1642x; 1.0094x over previous
//
#include <hip/hip_runtime.h>
#include <hip/hip_bf16.h>
#include <math.h>

#define NN 8192
#define HD 128
#define NB 2
#define EPSF 1e-6f
#define BM 64
#define BK 128
#define NSTEP (NN / BK)   // 64

typedef __attribute__((ext_vector_type(8))) __bf16 bf16x8;
typedef __attribute__((ext_vector_type(4))) float f32x4;

// ---------------- Kernel 1: norm = rsqrt(sum|adj_row| + eps) -----------------
// Non-temporal loads (R23-verified, -5 us): adj is not installed in L2/L3 by
// this pass, leaving the caches for the gemm's B panels.
__global__ __launch_bounds__(256) void k_degree(const float* __restrict__ adj,
                                                float* __restrict__ norm) {
    const int row  = blockIdx.x * 4 + (threadIdx.x >> 6);
    const int lane = threadIdx.x & 63;
    const f32x4* p = (const f32x4*)(adj + (size_t)row * NN);
    float s = 0.f;
#pragma unroll
    for (int i = 0; i < 32; ++i) {
        f32x4 v = __builtin_nontemporal_load(&p[(size_t)i * 64 + lane]);
        s += fabsf(v[0]) + fabsf(v[1]) + fabsf(v[2]) + fabsf(v[3]);
    }
#pragma unroll
    for (int off = 32; off > 0; off >>= 1) s += __shfl_down(s, off);
    if (lane == 0) norm[row] = rsqrtf(s + EPSF);
}

// --- Kernel 2: snT2[b][n/32][h][n&31] = bf16( (x@W)[b][n][h] * norm[b][n] ) --
// K-panel-major layout (R15-verified): gemm B loads are 1 KB/wave contiguous.
__global__ __launch_bounds__(256) void k_support(const float* __restrict__ x,
                                                 const float* __restrict__ W,
                                                 const float* __restrict__ norm,
                                                 __hip_bfloat16* __restrict__ snT2) {
    const int b  = blockIdx.x >> 9;
    const int n0 = (blockIdx.x & 511) * 16;
    __shared__ float xs[16][132];
    const int t = threadIdx.x;
    {
        const int r = t >> 4, c0 = (t & 15) * 8;
        const float* src = x + ((size_t)(b * NN + n0 + r)) * HD + c0;
        *(float4*)&xs[r][c0]     = *(const float4*)src;
        *(float4*)&xs[r][c0 + 4] = *(const float4*)(src + 4);
    }
    __syncthreads();
    const int nl = t & 15;
    const int h0 = (t >> 4) * 8;
    float s[8] = {0.f,0.f,0.f,0.f,0.f,0.f,0.f,0.f};
#pragma unroll 4
    for (int k = 0; k < HD; ++k) {
        const float xv = xs[nl][k];
        const float* wr = W + k * HD + h0;
        float4 wa = *(const float4*)wr;
        float4 wb = *(const float4*)(wr + 4);
        s[0] += xv * wa.x; s[1] += xv * wa.y; s[2] += xv * wa.z; s[3] += xv * wa.w;
        s[4] += xv * wb.x; s[5] += xv * wb.y; s[6] += xv * wb.z; s[7] += xv * wb.w;
    }
    const int n  = n0 + nl;
    const float nv = norm[b * NN + n];
    __hip_bfloat16* dst = snT2 + (size_t)b * NN * HD
                        + (size_t)(n >> 5) * (HD * 32) + (n & 31);
#pragma unroll
    for (int hb = 0; hb < 8; ++hb)
        dst[(h0 + hb) * 32] = __float2bfloat16(s[hb] * nv);
}

__device__ __forceinline__ bf16x8 cvt8(float4 a, float4 b) {
    bf16x8 r;
    r[0] = (__bf16)a.x; r[1] = (__bf16)a.y; r[2] = (__bf16)a.z; r[3] = (__bf16)a.w;
    r[4] = (__bf16)b.x; r[5] = (__bf16)b.y; r[6] = (__bf16)b.z; r[7] = (__bf16)b.w;
    return r;
}

// async global->LDS, 16 B per lane, NON-TEMPORAL (aux=2 = CPol::NT on gfx950):
// the A-stage stream is single-use and must not evict snT2 panels from the
// XCD L2 (B is re-read 128x; keeping it L2-resident is worth far more than
// caching A bytes that are never touched again).
__device__ __forceinline__ void gload_lds16_nt(const float* g, void* l) {
    __builtin_amdgcn_global_load_lds(
        (const __attribute__((address_space(1))) void*)g,
        (__attribute__((address_space(3))) void*)l, 16, 0, 2 /* NT */);
}

// ---- Kernel 3: out = elu( norm_m * (adj[b] @ support_norm^T) + bias ) -------
// R23 gemm verbatim except NT staging (single-variable change). BM=64
// counted-vmcnt pipeline: 512 threads = 8 waves = 2 m-halves x 4 h-slices;
// 4 x 32 KB LDS buffers; stage-ahead-2; B one step ahead in ping-pong banks.
// Per half-iter: B(k+1)[8] + stage(k+2)[4] -> WAITN(16) retires st(k), B(k).
// Both-sides XOR swizzle + panel-major coalesced B (absmax 0.015625, 9 rounds).
__global__ __launch_bounds__(512, 2) void k_gemm17(const float* __restrict__ adj,
                                                   const __hip_bfloat16* __restrict__ snT2,
                                                   const float* __restrict__ norm,
                                                   const float* __restrict__ bias,
                                                   float* __restrict__ out) {
    const int b    = blockIdx.y;
    const int swz  = (blockIdx.x & 7) * 16 + (blockIdx.x >> 3);   // XCD-bijective (128 = 8x16)
    const int m0   = swz * BM;
    const int w    = threadIdx.x >> 6;     // 0..7
    const int mh   = w & 1;                // m-half owner (32 rows)
    const int hs   = w >> 1;               // h-slice owner (32 h)
    const int lane = threadIdx.x & 63;
    const int fr   = lane & 15;
    const int g    = lane >> 4;
    const int xr   = fr & 7;

    const float* adjB = adj + (size_t)b * NN * NN;
    const __hip_bfloat16* snB = snT2 + (size_t)b * NN * HD;

    __shared__ __align__(16) char Abuf[4][BM * BK * 4];   // 4 x 32 KB

    // staging: thread call c covers 16B-granule fg = c*512 + w*64 + lane
    // (2048 granules = 64 rows x 32); row = fg>>5, slot = (fg&31)^(row&7).
    const float* sptr[4];
#pragma unroll
    for (int c = 0; c < 4; ++c) {
        const int fg   = c * 512 + w * 64 + lane;
        const int row  = fg >> 5;
        const int gsrc = (fg & 31) ^ (row & 7);
        sptr[c] = adjB + (size_t)(m0 + row) * NN + gsrc * 4;
    }

    // B base: panel-major; lane chunk = (hs*32 + ht*16 + fr)*32 + g*8
    const __hip_bfloat16* bp0 = snB + (size_t)(hs * 32 + fr) * 32 + g * 8;
    const __hip_bfloat16* bp1 = bp0 + 16 * 32;

    f32x4 acc[2][2] = {};   // [m-tile within half][h-tile]
    bf16x8 BfA[2][4], BfB[2][4];

#define STAGE(idx) do {                                                       \
        char* nb_ = Abuf[(idx) & 3];                                          \
        _Pragma("unroll")                                                     \
        for (int c = 0; c < 4; ++c)                                           \
            gload_lds16_nt(sptr[c] + (idx) * BK, &nb_[c * 8192 + w * 1024]);  \
    } while (0)
#define LOADB(BX, idx) do {                                                   \
        _Pragma("unroll")                                                     \
        for (int ks = 0; ks < 4; ++ks) {                                      \
            const size_t kp_ = (size_t)((idx) * 4 + ks) * (HD * 32);          \
            BX[0][ks] = *(const bf16x8*)(bp0 + kp_);                          \
            BX[1][ks] = *(const bf16x8*)(bp1 + kp_);                          \
        }                                                                     \
    } while (0)
#define WAITN(n) asm volatile("s_waitcnt vmcnt(" #n ")" ::: "memory")
#define BAR() do { __builtin_amdgcn_s_barrier();                              \
                   __builtin_amdgcn_sched_barrier(0); } while (0)
#define COMPUTE(kidx, BX) do {                                                \
        const char* lb_ = Abuf[(kidx) & 3];                                   \
        _Pragma("unroll")                                                     \
        for (int mt = 0; mt < 2; ++mt) {                                      \
            const char* rbase_ = lb_ + (mh * 32 + mt * 16 + fr) * 512;        \
            _Pragma("unroll")                                                 \
            for (int ks = 0; ks < 4; ++ks) {                                  \
                float4 fa_ = *(const float4*)(rbase_ + ((ks * 8 + ((g * 2 + 0) ^ xr)) << 4)); \
                float4 fb_ = *(const float4*)(rbase_ + ((ks * 8 + ((g * 2 + 1) ^ xr)) << 4)); \
                bf16x8 af_ = cvt8(fa_, fb_);                                  \
                acc[mt][0] = __builtin_amdgcn_mfma_f32_16x16x32_bf16(af_, BX[0][ks], acc[mt][0], 0, 0, 0); \
                acc[mt][1] = __builtin_amdgcn_mfma_f32_16x16x32_bf16(af_, BX[1][ks], acc[mt][1], 0, 0, 0); \
            }                                                                 \
        }                                                                     \
    } while (0)

    // ---- prologue: stage 0,1; B(0) into bank A ----
    STAGE(0);
    STAGE(1);
    LOADB(BfA, 0);

    // ---- main loop ----
#pragma unroll 1
    for (int k = 0; k < NSTEP - 3; k += 2) {
        LOADB(BfB, k + 1);
        STAGE(k + 2);
        WAITN(16); BAR();
        COMPUTE(k, BfA);

        LOADB(BfA, k + 2);
        STAGE(k + 3);
        WAITN(16); BAR();
        COMPUTE(k + 1, BfB);
    }

    // ---- tail ----
    LOADB(BfB, NSTEP - 1);
    WAITN(0); BAR();
    COMPUTE(NSTEP - 2, BfA);

    WAITN(0); BAR();
    COMPUTE(NSTEP - 1, BfB);

#undef STAGE
#undef LOADB
#undef WAITN
#undef BAR
#undef COMPUTE

    // ---- fused epilogue: *norm_m + bias, elu ----
    const float* normB = norm + b * NN + m0;
    float* outB = out + ((size_t)b * NN + m0) * HD;
#pragma unroll
    for (int mt = 0; mt < 2; ++mt)
#pragma unroll
        for (int ht = 0; ht < 2; ++ht) {
            const int h  = hs * 32 + ht * 16 + fr;
            const float bv = bias[h];
#pragma unroll
            for (int j = 0; j < 4; ++j) {
                const int r = mh * 32 + mt * 16 + g * 4 + j;
                float v = acc[mt][ht][j] * normB[r] + bv;
                v = v > 0.f ? v : expm1f(v);
                outB[(size_t)r * HD + h] = v;
            }
        }
}

extern "C" void kernel_launch(void* const* d_in, const int* in_sizes, int n_in,
                              void* d_out, int out_size, void* d_ws, size_t ws_size,
                              hipStream_t stream) {
    (void)in_sizes; (void)n_in; (void)out_size; (void)ws_size;
    const float* x    = (const float*)d_in[0];
    const float* adj  = (const float*)d_in[1];
    const float* W    = (const float*)d_in[2];
    const float* bias = (const float*)d_in[3];
    float* out = (float*)d_out;

    float* norm = (float*)d_ws;                                     // 16384 f32
    __hip_bfloat16* snT2 = (__hip_bfloat16*)((char*)d_ws + 65536);  // 4 MB, panel-major

    k_degree <<<dim3(NB * NN / 4),  dim3(256), 0, stream>>>(adj, norm);
    k_support<<<dim3(NB * NN / 16), dim3(256), 0, stream>>>(x, W, norm, snT2);
    k_gemm17 <<<dim3(NN / BM, NB),  dim3(512), 0, stream>>>(adj, snT2, norm, bias, out);
}